// Round 15
// baseline (3604.237 us; speedup 1.0000x reference)
//
#include <hip/hip_runtime.h>
#include <cstddef>
#include <cstdint>

#define BB 64
#define TT 512
#define HH 1024
#define DD 300
#define NTH 256
#define NBLK 128
#define HB 8                  // h-indices per block
#define XPAD 320              // x K padded to 10*32
#define KS_X 10
#define KS_H 32
#define BN_EPS 1e-5f

typedef short short8 __attribute__((ext_vector_type(8)));
typedef float f32x4 __attribute__((ext_vector_type(4)));
typedef unsigned u32x2 __attribute__((ext_vector_type(2)));
typedef unsigned u32x4 __attribute__((ext_vector_type(4)));

__device__ __forceinline__ float sigmoid_f(float v) {
  v = fminf(fmaxf(v, -30.f), 30.f);
  return 1.f / (1.f + __expf(-v));
}
__device__ __forceinline__ float tanh_f(float v) {
  float e = __expf(fminf(fmaxf(2.f * v, -30.f), 30.f));
  return (e - 1.f) / (e + 1.f);
}
__device__ __forceinline__ unsigned short tobf(float f) {
  unsigned u = __float_as_uint(f);
  u += 0x7fffu + ((u >> 16) & 1u);
  return (unsigned short)(u >> 16);
}

// ---- all in-loop vmem is inline asm so counted-vmcnt bookkeeping stays exact
__device__ __forceinline__ void ldA_sc(const void* p, short8& d) {
  asm volatile("global_load_dwordx4 %0, %1, off sc0 sc1"
               : "=v"(d) : "v"(p) : "memory");
}
__device__ __forceinline__ void ldA_nc(const void* p, short8& d) {
  asm volatile("global_load_dwordx4 %0, %1, off"
               : "=v"(d) : "v"(p) : "memory");
}
__device__ __forceinline__ void ld4_sc(const void* p, f32x4& d) {
  asm volatile("global_load_dwordx4 %0, %1, off sc0 sc1"
               : "=v"(d) : "v"(p) : "memory");
}
__device__ __forceinline__ u32x2 ld2w_sc(const void* p) {
  u32x2 v;
  asm volatile("global_load_dwordx2 %0, %1, off sc0 sc1\n\ts_waitcnt vmcnt(0)"
               : "=v"(v) : "v"(p) : "memory");
  return v;
}
__device__ __forceinline__ void st_sc32(void* p, unsigned v) {  // with drain
  asm volatile("global_store_dword %0, %1, off sc0 sc1\n\ts_waitcnt vmcnt(0)"
               :: "v"(p), "v"(v) : "memory");
}
__device__ __forceinline__ void st_sc32_nd(void* p, unsigned v) {  // no drain
  asm volatile("global_store_dword %0, %1, off sc0 sc1"
               :: "v"(p), "v"(v) : "memory");
}
__device__ __forceinline__ void st4_sc_nd(void* p, u32x4 v) {  // no drain
  asm volatile("global_store_dwordx4 %0, %1, off sc0 sc1"
               :: "v"(p), "v"(v) : "memory");
}
#define WAITV(N)                                                   \
  do {                                                             \
    asm volatile("s_waitcnt vmcnt(" #N ")" ::: "memory");          \
    __builtin_amdgcn_sched_barrier(0);                             \
  } while (0)

__device__ __forceinline__ f32x4 mfma16(short8 a, short8 b, f32x4 c) {
  return __builtin_amdgcn_mfma_f32_16x16x32_bf16(a, b, c, 0, 0, 0);
}

// wave0-only poll: lane i checks slots[2i], slots[2i+1]. Drained probes.
// PRECONDITION: wave0 enters only AFTER its own block's slot is raised.
// The first __syncthreads_and also serves as the Cs-protection barrier.
__device__ __forceinline__ void poll_ge(const unsigned* slots, int tid, unsigned ep) {
  int it = 0;
  for (;;) {
    int ok = 1;
    if (tid < 64) {
      u32x2 v = ld2w_sc(&slots[2 * tid]);
      ok = (v.x >= ep && v.y >= ep) ? 1 : 0;
    }
    if (__syncthreads_and(ok)) break;
    if (++it > (1 << 20)) break;  // valve: fail visibly, never hang
    if (it > 2) __builtin_amdgcn_s_sleep(1);
  }
}

__global__ void init_k(unsigned* __restrict__ base, int ndw) {
  int idx = blockIdx.x * blockDim.x + threadIdx.x;
  for (int i = idx; i < ndw; i += gridDim.x * blockDim.x) st_sc32(base + i, 0u);
}

// x [b][t][d] f32 -> xbf [t][b][XPAD] bf16 (zero-padded)
__global__ void xcvt_k(const float* __restrict__ x, unsigned short* __restrict__ xbf) {
  const int total = TT * BB * XPAD;
  for (int idx = blockIdx.x * blockDim.x + threadIdx.x; idx < total;
       idx += gridDim.x * blockDim.x) {
    int kx = idx % XPAD;
    int tb = idx / XPAD;
    int b = tb % BB, t = tb / BB;
    float v = (kx < DD) ? x[(size_t)b * (TT * DD) + (size_t)t * DD + kx] : 0.f;
    xbf[idx] = tobf(v);
  }
}

__global__ void __launch_bounds__(NTH, 1)
lstm_mfma(const float* __restrict__ Wih, const float* __restrict__ Whh,
          const float* __restrict__ bih, const float* __restrict__ bhh,
          const float* __restrict__ gammap, const float* __restrict__ betap,
          const float* __restrict__ maskp, const float* __restrict__ tlbl,
          const float* __restrict__ fcw, const float* __restrict__ fcb,
          const unsigned short* __restrict__ xbf, unsigned short* __restrict__ hbuf,
          float* __restrict__ partial, unsigned* __restrict__ slots,
          float* __restrict__ outp) {
  // B-operand fragments: Wlds[nt][ks][lane] = 8 bf16 of
  // B[k = ks*32 + (lane>>4)*8 + e][col = nt*16 + (lane&15)].
  // ks 0..31 = W_hh, 32..41 = W_ih (zero-padded). Lane-linear ds_read_b128.
  __shared__ short8 Wlds[2][KS_H + KS_X][64];  // 84 KB
  __shared__ float Cs[64][33];                 // 8.4 KB (+1 pad)
  __shared__ unsigned pkbuf[BB][4];            // 1 KB staged publish
  __shared__ float red_s[4][64];               // 1 KB

  const int tid = threadIdx.x;
  const int w = tid >> 6, l = tid & 63;
  const int blk = blockIdx.x;
  const int hb0 = blk * HB;

  // ---- stage W as bf16 fragments (once) ----
  for (int idx = tid; idx < 2 * (KS_H + KS_X) * 64; idx += NTH) {
    int nt = idx / ((KS_H + KS_X) * 64);
    int rem = idx % ((KS_H + KS_X) * 64);
    int ks = rem >> 6, ll = rem & 63;
    int colq = nt * 16 + (ll & 15);
    int g = colq >> 3, j = colq & 7;
    int r = g * HH + hb0 + j;
    int k0 = (ll >> 4) * 8;
    float v[8];
    if (ks < KS_H) {
      const float* src = Whh + (size_t)r * HH + ks * 32 + k0;
      f32x4 u0 = *(const f32x4*)src;
      f32x4 u1 = *(const f32x4*)(src + 4);
      v[0] = u0.x; v[1] = u0.y; v[2] = u0.z; v[3] = u0.w;
      v[4] = u1.x; v[5] = u1.y; v[6] = u1.z; v[7] = u1.w;
    } else {
      int d0 = (ks - KS_H) * 32 + k0;
#pragma unroll
      for (int e = 0; e < 8; ++e)
        v[e] = (d0 + e < DD) ? Wih[(size_t)r * DD + d0 + e] : 0.f;
    }
    short8 pk;
#pragma unroll
    for (int e = 0; e < 8; ++e) pk[e] = (short)tobf(v[e]);
    Wlds[nt][ks][ll] = pk;
  }

  // ---- MFMA roles: wave = M-tile; computes both N-tiles ----
  const int row = w * 16 + (l & 15);
  const int lk16 = (l >> 4);

  // per-column combined bias (folded into acc init)
  const int cq = l & 15;
  const float bcol0 = bih[(cq >> 3) * HH + hb0 + (cq & 7)] +
                      bhh[(cq >> 3) * HH + hb0 + (cq & 7)];
  const float bcol1 = bih[(2 + (cq >> 3)) * HH + hb0 + (cq & 7)] +
                      bhh[(2 + (cq >> 3)) * HH + hb0 + (cq & 7)];

  // ---- pointwise roles: lane = batch, wave w -> h-sub j0=2w, j1=2w+1 ----
  const int b = l, j0 = 2 * w, j1 = 2 * w + 1;
  const float gam0 = gammap[hb0 + j0], gam1 = gammap[hb0 + j1];
  const float bet0 = betap[hb0 + j0], bet1 = betap[hb0 + j1];
  const float msk0 = maskp[(size_t)b * HH + hb0 + j0];
  const float msk1 = maskp[(size_t)b * HH + hb0 + j1];
  const float fw0 = fcw[hb0 + j0], fw1 = fcw[hb0 + j1];
  float creg0 = 0.f, creg1 = 0.f;
  float pool0 = -3.4e38f, pool1 = -3.4e38f;
  float ph20 = 0.f, ph21 = 0.f;  // previous step's h (BN deferred one step)

  // prologue: issue x-loads for s=0
  short8 xa[KS_X];
  {
    const unsigned short* px = xbf + ((size_t)0 * BB + row) * XPAD + lk16 * 8;
#pragma unroll
    for (int i = 0; i < KS_X; ++i) ldA_nc(px + i * 32, xa[i]);
  }
  __syncthreads();  // Wlds visible

  for (int s = 0; s < TT; ++s) {
    const unsigned short* hc = hbuf + (size_t)(s & 1) * (BB * HH);
    unsigned short* hnx = hbuf + (size_t)((s + 1) & 1) * (BB * HH);

    // wait for h_s publication (s=0 passes immediately; own slot already
    // raised by THIS wave0 before it entered the poll). The poll's internal
    // __syncthreads_and also protects Cs/pkbuf across iterations.
    poll_ge(slots, tid, (unsigned)s);

    // issue ALL 32 h A-frag loads (addr = hc + (ks*4 + lk16)*512 + row*8)
    const unsigned short* ph = hc + (size_t)lk16 * 512 + row * 8;
    short8 ha[KS_H];
#pragma unroll
    for (int i = 0; i < KS_H; ++i) ldA_sc(ph + i * 2048, ha[i]);

    // ---- BN + pool of PREVIOUS step: pure VALU/shuffle, runs in the
    // h-load round-trip shadow; no vmem -> ledger untouched ----
    if (s > 0) {
      float s10 = ph20, s20 = ph20 * ph20, s11 = ph21, s21 = ph21 * ph21;
#pragma unroll
      for (int off = 32; off; off >>= 1) {
        s10 += __shfl_xor(s10, off, 64);
        s20 += __shfl_xor(s20, off, 64);
        s11 += __shfl_xor(s11, off, 64);
        s21 += __shfl_xor(s21, off, 64);
      }
      float mu0 = s10 * (1.f / 64.f), var0 = fmaf(-mu0, mu0, s20 * (1.f / 64.f));
      float mu1 = s11 * (1.f / 64.f), var1 = fmaf(-mu1, mu1, s21 * (1.f / 64.f));
      pool0 = fmaxf(pool0, (gam0 * (ph20 - mu0) * rsqrtf(var0 + BN_EPS) + bet0) * msk0);
      pool1 = fmaxf(pool1, (gam1 * (ph21 - mu1) * rsqrtf(var1 + BN_EPS) + bet1) * msk1);
    }

    // Per-wave queues here: w0 = [h32] (x+pub drained at its WAITV(0), slot
    // drained by poll probe), w1-3 = [x10, h32] = 42 -> WAITV(32) retires x
    // exactly (x had pointwise+publish+poll window to land).
    WAITV(32);

    // x-MFMAs while h chunk0 is in flight; 4 independent acc chains
    f32x4 acc0a = {bcol0, bcol0, bcol0, bcol0}, acc0b = {0.f, 0.f, 0.f, 0.f};
    f32x4 acc1a = {bcol1, bcol1, bcol1, bcol1}, acc1b = {0.f, 0.f, 0.f, 0.f};
#pragma unroll
    for (int i = 0; i < KS_X; i += 2) {
      acc0a = mfma16(xa[i], Wlds[0][KS_H + i][l], acc0a);
      acc1a = mfma16(xa[i], Wlds[1][KS_H + i][l], acc1a);
      acc0b = mfma16(xa[i + 1], Wlds[0][KS_H + i + 1][l], acc0b);
      acc1b = mfma16(xa[i + 1], Wlds[1][KS_H + i + 1][l], acc1b);
    }
    WAITV(24);  // h chunk0 (loads 0..7) done
#pragma unroll
    for (int i = 0; i < 8; i += 2) {
      acc0a = mfma16(ha[i], Wlds[0][i][l], acc0a);
      acc1a = mfma16(ha[i], Wlds[1][i][l], acc1a);
      acc0b = mfma16(ha[i + 1], Wlds[0][i + 1][l], acc0b);
      acc1b = mfma16(ha[i + 1], Wlds[1][i + 1][l], acc1b);
    }
    WAITV(16);  // chunk1
#pragma unroll
    for (int i = 8; i < 16; i += 2) {
      acc0a = mfma16(ha[i], Wlds[0][i][l], acc0a);
      acc1a = mfma16(ha[i], Wlds[1][i][l], acc1a);
      acc0b = mfma16(ha[i + 1], Wlds[0][i + 1][l], acc0b);
      acc1b = mfma16(ha[i + 1], Wlds[1][i + 1][l], acc1b);
    }
    WAITV(8);  // chunk2
#pragma unroll
    for (int i = 16; i < 24; i += 2) {
      acc0a = mfma16(ha[i], Wlds[0][i][l], acc0a);
      acc1a = mfma16(ha[i], Wlds[1][i][l], acc1a);
      acc0b = mfma16(ha[i + 1], Wlds[0][i + 1][l], acc0b);
      acc1b = mfma16(ha[i + 1], Wlds[1][i + 1][l], acc1b);
    }
    WAITV(0);  // chunk3
#pragma unroll
    for (int i = 24; i < 32; i += 2) {
      acc0a = mfma16(ha[i], Wlds[0][i][l], acc0a);
      acc1a = mfma16(ha[i], Wlds[1][i][l], acc1a);
      acc0b = mfma16(ha[i + 1], Wlds[0][i + 1][l], acc0b);
      acc1b = mfma16(ha[i + 1], Wlds[1][i + 1][l], acc1b);
    }
    f32x4 acc0 = acc0a + acc0b, acc1 = acc1a + acc1b;

    // ---- C exchange via LDS (C: col=lane&15, row=(lane>>4)*4+r) ----
    {
      int crow = w * 16 + (l >> 4) * 4;
      int cc0 = (l & 15), cc1 = 16 + (l & 15);
#pragma unroll
      for (int r = 0; r < 4; ++r) {
        Cs[crow + r][cc0] = acc0[r];
        Cs[crow + r][cc1] = acc1[r];
      }
    }
    __syncthreads();

    // ---- x prefetch for s+1 (has pointwise+publish+poll window to land;
    // retired at wave0's WAITV(0) / others' WAITV(32)) ----
    {
      int sx = (s + 1 < TT) ? s + 1 : s;  // uniform ledger on last iter
      const unsigned short* px = xbf + ((size_t)sx * BB + row) * XPAD + lk16 * 8;
#pragma unroll
      for (int i = 0; i < KS_X; ++i) ldA_nc(px + i * 32, xa[i]);
    }

    // ---- pointwise-lite: ONLY what the recurrence needs (BN deferred) ----
    float gI0 = Cs[b][j0],      gF0 = Cs[b][8 + j0];
    float gG0 = Cs[b][16 + j0], gO0 = Cs[b][24 + j0];
    float gI1 = Cs[b][j1],      gF1 = Cs[b][8 + j1];
    float gG1 = Cs[b][16 + j1], gO1 = Cs[b][24 + j1];
    float c20 = sigmoid_f(gF0) * creg0 + sigmoid_f(gI0) * tanh_f(gG0);
    float h20 = sigmoid_f(gO0) * tanh_f(c20);
    float c21 = sigmoid_f(gF1) * creg1 + sigmoid_f(gI1) * tanh_f(gG1);
    float h21 = sigmoid_f(gO1) * tanh_f(c21);
    creg0 = c20;
    creg1 = c21;
    ph20 = h20;  // carry for next step's shadowed BN
    ph21 = h21;
    pkbuf[b][w] = (unsigned)tobf(h20) | ((unsigned)tobf(h21) << 16);
    __syncthreads();

    // ---- wave0: full-line 1KB publish + drain + fire-forget slot, THEN it
    // enters the poll (own slot guaranteed raised before first probe).
    // No BN here anymore: wave0's probe starts ~0.2us earlier. ----
    if (w == 0) {
      u32x4 pv = {pkbuf[l][0], pkbuf[l][1], pkbuf[l][2], pkbuf[l][3]};
      st4_sc_nd(hnx + (size_t)blk * 512 + l * 8, pv);
      WAITV(0);  // drains publish + this wave's x-prefetch (1 LLC RT)
      if (l == 0) st_sc32_nd(&slots[blk], (unsigned)(s + 1));
    }
    // (loop-end __syncthreads removed: poll's __syncthreads_and covers Cs)
  }

  // ---- final BN + pool for s = TT-1 (deferred) ----
  {
    float s10 = ph20, s20 = ph20 * ph20, s11 = ph21, s21 = ph21 * ph21;
#pragma unroll
    for (int off = 32; off; off >>= 1) {
      s10 += __shfl_xor(s10, off, 64);
      s20 += __shfl_xor(s20, off, 64);
      s11 += __shfl_xor(s11, off, 64);
      s21 += __shfl_xor(s21, off, 64);
    }
    float mu0 = s10 * (1.f / 64.f), var0 = fmaf(-mu0, mu0, s20 * (1.f / 64.f));
    float mu1 = s11 * (1.f / 64.f), var1 = fmaf(-mu1, mu1, s21 * (1.f / 64.f));
    pool0 = fmaxf(pool0, (gam0 * (ph20 - mu0) * rsqrtf(var0 + BN_EPS) + bet0) * msk0);
    pool1 = fmaxf(pool1, (gam1 * (ph21 - mu1) * rsqrtf(var1 + BN_EPS) + bet1) * msk1);
  }
  WAITV(0);  // clean ledger (w0: slot; w1-3: x10)

  // ---- per-block FC partial ----
  red_s[w][b] = pool0 * fw0 + pool1 * fw1;
  __syncthreads();
  if (tid < BB) {
    float part = red_s[0][tid] + red_s[1][tid] + red_s[2][tid] + red_s[3][tid];
    st_sc32(&partial[(size_t)tid * NBLK + blk], __float_as_uint(part));
  }
  __syncthreads();
  if (tid == 0) st_sc32_nd(&slots[blk], (unsigned)(TT + 2));
  if (blk != 0) return;

  // ---- block 0: final reduction + loss ----
  poll_ge(slots, tid, (unsigned)(TT + 2));
  {
    int fb = tid & 63, q = tid >> 6;
    const float* pp = partial + ((size_t)fb * NBLK + q * 32);
    f32x4 v0, v1, v2, v3, v4, v5, v6, v7;
    ld4_sc(pp + 0, v0);  ld4_sc(pp + 4, v1);  ld4_sc(pp + 8, v2);  ld4_sc(pp + 12, v3);
    ld4_sc(pp + 16, v4); ld4_sc(pp + 20, v5); ld4_sc(pp + 24, v6); ld4_sc(pp + 28, v7);
    WAITV(0);
    float sum = v0.x + v0.y + v0.z + v0.w + v1.x + v1.y + v1.z + v1.w +
                v2.x + v2.y + v2.z + v2.w + v3.x + v3.y + v3.z + v3.w +
                v4.x + v4.y + v4.z + v4.w + v5.x + v5.y + v5.z + v5.w +
                v6.x + v6.y + v6.z + v6.w + v7.x + v7.y + v7.z + v7.w;
    red_s[q][fb] = sum;
  }
  __syncthreads();
  if (tid < BB) {
    float z = red_s[0][tid] + red_s[1][tid] + red_s[2][tid] + red_s[3][tid] + fcb[0];
    outp[1 + tid] = z;
    float sp = fmaxf(z, 0.f) + log1pf(__expf(-fabsf(z)));
    float lt = sp - z * tlbl[tid];
#pragma unroll
    for (int off = 32; off; off >>= 1) lt += __shfl_xor(lt, off, 64);
    if (tid == 0) outp[0] = lt * (1.f / 64.f);
  }
}

extern "C" void kernel_launch(void* const* d_in, const int* in_sizes, int n_in,
                              void* d_out, int out_size, void* d_ws, size_t ws_size,
                              hipStream_t stream) {
  const float* x = (const float*)d_in[0];
  const float* tlbl = (const float*)d_in[1];
  const float* maskp = (const float*)d_in[2];
  const float* Wih = (const float*)d_in[3];
  const float* Whh = (const float*)d_in[4];
  const float* bih = (const float*)d_in[5];
  const float* bhh = (const float*)d_in[6];
  const float* gammap = (const float*)d_in[7];
  const float* betap = (const float*)d_in[8];
  const float* fcw = (const float*)d_in[9];
  const float* fcb = (const float*)d_in[10];
  float* outp = (float*)d_out;

  // ws: slots(512B)+pad @0 | hbuf 2x128KB @4KB | partial 32KB | xbf 20.5MB
  unsigned* slots = (unsigned*)d_ws;
  unsigned short* hbuf = (unsigned short*)((char*)d_ws + 4096);
  float* partial = (float*)((char*)d_ws + 4096 + 2 * BB * HH * 2);
  unsigned short* xbf =
      (unsigned short*)((char*)d_ws + 4096 + 2 * BB * HH * 2 + BB * NBLK * 4);

  // zero slots + h image 0 (contiguous from ws base: 4096 + 128KB)
  int ndw = (4096 + BB * HH * 2) / 4;
  hipLaunchKernelGGL(init_k, dim3(64), dim3(NTH), 0, stream, (unsigned*)d_ws, ndw);
  hipLaunchKernelGGL(xcvt_k, dim3(2048), dim3(NTH), 0, stream, x, xbf);
  hipLaunchKernelGGL(lstm_mfma, dim3(NBLK), dim3(NTH), 0, stream,
                     Wih, Whh, bih, bhh, gammap, betap, maskp, tlbl, fcw, fcb,
                     xbf, hbuf, partial, slots, outp);
}

// Round 16
// 2655.392 us; speedup vs baseline: 1.3573x; 1.3573x over previous
//
#include <hip/hip_runtime.h>
#include <cstddef>
#include <cstdint>

#define BB 64
#define TT 512
#define HH 1024
#define DD 300
#define NTH 256
#define NBLK 128
#define HB 8                  // h-indices per block
#define XPAD 320              // x K padded to 10*32
#define KS_X 10
#define KS_H 32
#define BN_EPS 1e-5f

typedef short short8 __attribute__((ext_vector_type(8)));
typedef float f32x4 __attribute__((ext_vector_type(4)));
typedef unsigned u32x2 __attribute__((ext_vector_type(2)));
typedef unsigned u32x4 __attribute__((ext_vector_type(4)));

__device__ __forceinline__ float sigmoid_f(float v) {
  v = fminf(fmaxf(v, -30.f), 30.f);
  return 1.f / (1.f + __expf(-v));
}
__device__ __forceinline__ float tanh_f(float v) {
  float e = __expf(fminf(fmaxf(2.f * v, -30.f), 30.f));
  return (e - 1.f) / (e + 1.f);
}
__device__ __forceinline__ unsigned short tobf(float f) {
  unsigned u = __float_as_uint(f);
  u += 0x7fffu + ((u >> 16) & 1u);
  return (unsigned short)(u >> 16);
}

// ---- all in-loop vmem is inline asm so counted-vmcnt bookkeeping stays exact
__device__ __forceinline__ void ldA_sc(const void* p, short8& d) {
  asm volatile("global_load_dwordx4 %0, %1, off sc0 sc1"
               : "=v"(d) : "v"(p) : "memory");
}
__device__ __forceinline__ void ldA_nc(const void* p, short8& d) {
  asm volatile("global_load_dwordx4 %0, %1, off"
               : "=v"(d) : "v"(p) : "memory");
}
__device__ __forceinline__ void ld4_sc(const void* p, f32x4& d) {
  asm volatile("global_load_dwordx4 %0, %1, off sc0 sc1"
               : "=v"(d) : "v"(p) : "memory");
}
__device__ __forceinline__ u32x2 ld2w_sc(const void* p) {
  u32x2 v;
  asm volatile("global_load_dwordx2 %0, %1, off sc0 sc1\n\ts_waitcnt vmcnt(0)"
               : "=v"(v) : "v"(p) : "memory");
  return v;
}
__device__ __forceinline__ void st_sc32(void* p, unsigned v) {  // with drain
  asm volatile("global_store_dword %0, %1, off sc0 sc1\n\ts_waitcnt vmcnt(0)"
               :: "v"(p), "v"(v) : "memory");
}
__device__ __forceinline__ void st_sc32_nd(void* p, unsigned v) {  // no drain
  asm volatile("global_store_dword %0, %1, off sc0 sc1"
               :: "v"(p), "v"(v) : "memory");
}
__device__ __forceinline__ void st4_sc_nd(void* p, u32x4 v) {  // no drain
  asm volatile("global_store_dwordx4 %0, %1, off sc0 sc1"
               :: "v"(p), "v"(v) : "memory");
}
#define WAITV(N)                                                   \
  do {                                                             \
    asm volatile("s_waitcnt vmcnt(" #N ")" ::: "memory");          \
    __builtin_amdgcn_sched_barrier(0);                             \
  } while (0)

__device__ __forceinline__ f32x4 mfma16(short8 a, short8 b, f32x4 c) {
  return __builtin_amdgcn_mfma_f32_16x16x32_bf16(a, b, c, 0, 0, 0);
}

// wave0-only poll: lane i checks slots[2i], slots[2i+1]. Drained probes.
// PRECONDITION: wave0 calls this only AFTER its own block's slot is raised
// -> first probe can succeed; no own-slot race.
__device__ __forceinline__ void poll_ge(const unsigned* slots, int tid, unsigned ep) {
  int it = 0;
  for (;;) {
    int ok = 1;
    if (tid < 64) {
      u32x2 v = ld2w_sc(&slots[2 * tid]);
      ok = (v.x >= ep && v.y >= ep) ? 1 : 0;
    }
    if (__syncthreads_and(ok)) break;
    if (++it > (1 << 20)) break;  // valve: fail visibly, never hang
    if (it > 2) __builtin_amdgcn_s_sleep(1);
  }
}

__global__ void init_k(unsigned* __restrict__ base, int ndw) {
  int idx = blockIdx.x * blockDim.x + threadIdx.x;
  for (int i = idx; i < ndw; i += gridDim.x * blockDim.x) st_sc32(base + i, 0u);
}

// x [b][t][d] f32 -> xbf [t][b][XPAD] bf16 (zero-padded)
__global__ void xcvt_k(const float* __restrict__ x, unsigned short* __restrict__ xbf) {
  const int total = TT * BB * XPAD;
  for (int idx = blockIdx.x * blockDim.x + threadIdx.x; idx < total;
       idx += gridDim.x * blockDim.x) {
    int kx = idx % XPAD;
    int tb = idx / XPAD;
    int b = tb % BB, t = tb / BB;
    float v = (kx < DD) ? x[(size_t)b * (TT * DD) + (size_t)t * DD + kx] : 0.f;
    xbf[idx] = tobf(v);
  }
}

__global__ void __launch_bounds__(NTH, 1)
lstm_mfma(const float* __restrict__ Wih, const float* __restrict__ Whh,
          const float* __restrict__ bih, const float* __restrict__ bhh,
          const float* __restrict__ gammap, const float* __restrict__ betap,
          const float* __restrict__ maskp, const float* __restrict__ tlbl,
          const float* __restrict__ fcw, const float* __restrict__ fcb,
          const unsigned short* __restrict__ xbf, unsigned short* __restrict__ hbuf,
          float* __restrict__ partial, unsigned* __restrict__ slots,
          float* __restrict__ outp) {
  // B-operand fragments: Wlds[nt][ks][lane] = 8 bf16 of
  // B[k = ks*32 + (lane>>4)*8 + e][col = nt*16 + (lane&15)].
  // ks 0..31 = W_hh, 32..41 = W_ih (zero-padded). Lane-linear ds_read_b128.
  __shared__ short8 Wlds[2][KS_H + KS_X][64];  // 84 KB
  __shared__ float Cs[64][33];                 // 8.4 KB (+1 pad)
  __shared__ unsigned pkbuf[BB][4];            // 1 KB staged publish
  __shared__ float red_s[4][64];               // 1 KB

  const int tid = threadIdx.x;
  const int w = tid >> 6, l = tid & 63;
  const int blk = blockIdx.x;
  const int hb0 = blk * HB;

  // ---- stage W as bf16 fragments (once) ----
  for (int idx = tid; idx < 2 * (KS_H + KS_X) * 64; idx += NTH) {
    int nt = idx / ((KS_H + KS_X) * 64);
    int rem = idx % ((KS_H + KS_X) * 64);
    int ks = rem >> 6, ll = rem & 63;
    int colq = nt * 16 + (ll & 15);
    int g = colq >> 3, j = colq & 7;
    int r = g * HH + hb0 + j;
    int k0 = (ll >> 4) * 8;
    float v[8];
    if (ks < KS_H) {
      const float* src = Whh + (size_t)r * HH + ks * 32 + k0;
      f32x4 u0 = *(const f32x4*)src;
      f32x4 u1 = *(const f32x4*)(src + 4);
      v[0] = u0.x; v[1] = u0.y; v[2] = u0.z; v[3] = u0.w;
      v[4] = u1.x; v[5] = u1.y; v[6] = u1.z; v[7] = u1.w;
    } else {
      int d0 = (ks - KS_H) * 32 + k0;
#pragma unroll
      for (int e = 0; e < 8; ++e)
        v[e] = (d0 + e < DD) ? Wih[(size_t)r * DD + d0 + e] : 0.f;
    }
    short8 pk;
#pragma unroll
    for (int e = 0; e < 8; ++e) pk[e] = (short)tobf(v[e]);
    Wlds[nt][ks][ll] = pk;
  }

  // ---- MFMA roles: wave = M-tile; computes both N-tiles ----
  const int row = w * 16 + (l & 15);
  const int lk16 = (l >> 4);

  // per-column combined bias (folded into acc init)
  const int cq = l & 15;
  const float bcol0 = bih[(cq >> 3) * HH + hb0 + (cq & 7)] +
                      bhh[(cq >> 3) * HH + hb0 + (cq & 7)];
  const float bcol1 = bih[(2 + (cq >> 3)) * HH + hb0 + (cq & 7)] +
                      bhh[(2 + (cq >> 3)) * HH + hb0 + (cq & 7)];

  // ---- pointwise roles: lane = batch, wave w -> h-sub j0=2w, j1=2w+1 ----
  const int b = l, j0 = 2 * w, j1 = 2 * w + 1;
  const float gam0 = gammap[hb0 + j0], gam1 = gammap[hb0 + j1];
  const float bet0 = betap[hb0 + j0], bet1 = betap[hb0 + j1];
  const float msk0 = maskp[(size_t)b * HH + hb0 + j0];
  const float msk1 = maskp[(size_t)b * HH + hb0 + j1];
  const float fw0 = fcw[hb0 + j0], fw1 = fcw[hb0 + j1];
  float creg0 = 0.f, creg1 = 0.f;
  float pool0 = -3.4e38f, pool1 = -3.4e38f;

  // prologue: issue x-loads for s=0
  short8 xa[KS_X];
  {
    const unsigned short* px = xbf + ((size_t)0 * BB + row) * XPAD + lk16 * 8;
#pragma unroll
    for (int i = 0; i < KS_X; ++i) ldA_nc(px + i * 32, xa[i]);
  }
  __syncthreads();  // Wlds visible

  for (int s = 0; s < TT; ++s) {
    const unsigned short* hc = hbuf + (size_t)(s & 1) * (BB * HH);
    unsigned short* hnx = hbuf + (size_t)((s + 1) & 1) * (BB * HH);

    // wait for h_s publication (s=0 passes immediately; own slot already
    // raised by THIS wave0 before it entered the poll -> no own-slot race)
    poll_ge(slots, tid, (unsigned)s);

    // issue ALL 32 h A-frag loads (addr = hc + (ks*4 + lk16)*512 + row*8)
    const unsigned short* ph = hc + (size_t)lk16 * 512 + row * 8;
    short8 ha[KS_H];
#pragma unroll
    for (int i = 0; i < KS_H; ++i) ldA_sc(ph + i * 2048, ha[i]);

    // Per-wave queues here: w0 = [h32] (x+pub drained at its WAITV(0), slot
    // drained by poll probe), w1-3 = [x10, h32] = 42 -> WAITV(32) retires x
    // exactly (x had pointwise+publish+poll window to land).
    WAITV(32);

    // x-MFMAs while h chunk0 is in flight; 4 independent acc chains
    f32x4 acc0a = {bcol0, bcol0, bcol0, bcol0}, acc0b = {0.f, 0.f, 0.f, 0.f};
    f32x4 acc1a = {bcol1, bcol1, bcol1, bcol1}, acc1b = {0.f, 0.f, 0.f, 0.f};
#pragma unroll
    for (int i = 0; i < KS_X; i += 2) {
      acc0a = mfma16(xa[i], Wlds[0][KS_H + i][l], acc0a);
      acc1a = mfma16(xa[i], Wlds[1][KS_H + i][l], acc1a);
      acc0b = mfma16(xa[i + 1], Wlds[0][KS_H + i + 1][l], acc0b);
      acc1b = mfma16(xa[i + 1], Wlds[1][KS_H + i + 1][l], acc1b);
    }
    WAITV(24);  // h chunk0 (loads 0..7) done
#pragma unroll
    for (int i = 0; i < 8; i += 2) {
      acc0a = mfma16(ha[i], Wlds[0][i][l], acc0a);
      acc1a = mfma16(ha[i], Wlds[1][i][l], acc1a);
      acc0b = mfma16(ha[i + 1], Wlds[0][i + 1][l], acc0b);
      acc1b = mfma16(ha[i + 1], Wlds[1][i + 1][l], acc1b);
    }
    WAITV(16);  // chunk1
#pragma unroll
    for (int i = 8; i < 16; i += 2) {
      acc0a = mfma16(ha[i], Wlds[0][i][l], acc0a);
      acc1a = mfma16(ha[i], Wlds[1][i][l], acc1a);
      acc0b = mfma16(ha[i + 1], Wlds[0][i + 1][l], acc0b);
      acc1b = mfma16(ha[i + 1], Wlds[1][i + 1][l], acc1b);
    }
    WAITV(8);  // chunk2
#pragma unroll
    for (int i = 16; i < 24; i += 2) {
      acc0a = mfma16(ha[i], Wlds[0][i][l], acc0a);
      acc1a = mfma16(ha[i], Wlds[1][i][l], acc1a);
      acc0b = mfma16(ha[i + 1], Wlds[0][i + 1][l], acc0b);
      acc1b = mfma16(ha[i + 1], Wlds[1][i + 1][l], acc1b);
    }
    WAITV(0);  // chunk3
#pragma unroll
    for (int i = 24; i < 32; i += 2) {
      acc0a = mfma16(ha[i], Wlds[0][i][l], acc0a);
      acc1a = mfma16(ha[i], Wlds[1][i][l], acc1a);
      acc0b = mfma16(ha[i + 1], Wlds[0][i + 1][l], acc0b);
      acc1b = mfma16(ha[i + 1], Wlds[1][i + 1][l], acc1b);
    }
    f32x4 acc0 = acc0a + acc0b, acc1 = acc1a + acc1b;

    // ---- C exchange via LDS (C: col=lane&15, row=(lane>>4)*4+r) ----
    {
      int crow = w * 16 + (l >> 4) * 4;
      int cc0 = (l & 15), cc1 = 16 + (l & 15);
#pragma unroll
      for (int r = 0; r < 4; ++r) {
        Cs[crow + r][cc0] = acc0[r];
        Cs[crow + r][cc1] = acc1[r];
      }
    }
    __syncthreads();

    // ---- x prefetch for s+1 (r5's proven position: has pointwise+publish
    // +poll window to land; retired at wave0's WAITV(0) / others' WAITV(32))
    {
      int sx = (s + 1 < TT) ? s + 1 : s;  // uniform ledger on last iter
      const unsigned short* px = xbf + ((size_t)sx * BB + row) * XPAD + lk16 * 8;
#pragma unroll
      for (int i = 0; i < KS_X; ++i) ldA_nc(px + i * 32, xa[i]);
    }

    // ---- pointwise-lite: ONLY what the recurrence needs (BN deferred) ----
    float gI0 = Cs[b][j0],      gF0 = Cs[b][8 + j0];
    float gG0 = Cs[b][16 + j0], gO0 = Cs[b][24 + j0];
    float gI1 = Cs[b][j1],      gF1 = Cs[b][8 + j1];
    float gG1 = Cs[b][16 + j1], gO1 = Cs[b][24 + j1];
    float c20 = sigmoid_f(gF0) * creg0 + sigmoid_f(gI0) * tanh_f(gG0);
    float h20 = sigmoid_f(gO0) * tanh_f(c20);
    float c21 = sigmoid_f(gF1) * creg1 + sigmoid_f(gI1) * tanh_f(gG1);
    float h21 = sigmoid_f(gO1) * tanh_f(c21);
    creg0 = c20;
    creg1 = c21;
    pkbuf[b][w] = (unsigned)tobf(h20) | ((unsigned)tobf(h21) << 16);
    __syncthreads();

    // ---- wave0: full-line 1KB publish + drain + fire-forget slot, THEN it
    // enters the poll (own slot guaranteed raised before first probe) ----
    if (w == 0) {
      u32x4 pv = {pkbuf[l][0], pkbuf[l][1], pkbuf[l][2], pkbuf[l][3]};
      st4_sc_nd(hnx + (size_t)blk * 512 + l * 8, pv);
      WAITV(0);  // drains publish + this wave's x-prefetch (1 LLC RT)
      if (l == 0) st_sc32_nd(&slots[blk], (unsigned)(s + 1));
    }

    // ---- BN + pool: OFF the critical chain (waves 1-3 run this under
    // wave0's publish drain; wave0 runs it after the slot raise) ----
    {
      float s10 = h20, s20 = h20 * h20, s11 = h21, s21 = h21 * h21;
#pragma unroll
      for (int off = 32; off; off >>= 1) {
        s10 += __shfl_xor(s10, off, 64);
        s20 += __shfl_xor(s20, off, 64);
        s11 += __shfl_xor(s11, off, 64);
        s21 += __shfl_xor(s21, off, 64);
      }
      float mu0 = s10 * (1.f / 64.f), var0 = fmaf(-mu0, mu0, s20 * (1.f / 64.f));
      float mu1 = s11 * (1.f / 64.f), var1 = fmaf(-mu1, mu1, s21 * (1.f / 64.f));
      float hn0 = gam0 * (h20 - mu0) * rsqrtf(var0 + BN_EPS) + bet0;
      float hn1 = gam1 * (h21 - mu1) * rsqrtf(var1 + BN_EPS) + bet1;
      pool0 = fmaxf(pool0, hn0 * msk0);
      pool1 = fmaxf(pool1, hn1 * msk1);
    }
  }

  // ---- per-block FC partial ----
  red_s[w][b] = pool0 * fw0 + pool1 * fw1;
  __syncthreads();
  if (tid < BB) {
    float part = red_s[0][tid] + red_s[1][tid] + red_s[2][tid] + red_s[3][tid];
    st_sc32(&partial[(size_t)tid * NBLK + blk], __float_as_uint(part));
  }
  __syncthreads();
  if (tid == 0) st_sc32_nd(&slots[blk], (unsigned)(TT + 2));
  if (blk != 0) return;

  // ---- block 0: final reduction + loss ----
  poll_ge(slots, tid, (unsigned)(TT + 2));
  {
    int fb = tid & 63, q = tid >> 6;
    const float* pp = partial + ((size_t)fb * NBLK + q * 32);
    f32x4 v0, v1, v2, v3, v4, v5, v6, v7;
    ld4_sc(pp + 0, v0);  ld4_sc(pp + 4, v1);  ld4_sc(pp + 8, v2);  ld4_sc(pp + 12, v3);
    ld4_sc(pp + 16, v4); ld4_sc(pp + 20, v5); ld4_sc(pp + 24, v6); ld4_sc(pp + 28, v7);
    WAITV(0);
    float sum = v0.x + v0.y + v0.z + v0.w + v1.x + v1.y + v1.z + v1.w +
                v2.x + v2.y + v2.z + v2.w + v3.x + v3.y + v3.z + v3.w +
                v4.x + v4.y + v4.z + v4.w + v5.x + v5.y + v5.z + v5.w +
                v6.x + v6.y + v6.z + v6.w + v7.x + v7.y + v7.z + v7.w;
    red_s[q][fb] = sum;
  }
  __syncthreads();
  if (tid < BB) {
    float z = red_s[0][tid] + red_s[1][tid] + red_s[2][tid] + red_s[3][tid] + fcb[0];
    outp[1 + tid] = z;
    float sp = fmaxf(z, 0.f) + log1pf(__expf(-fabsf(z)));
    float lt = sp - z * tlbl[tid];
#pragma unroll
    for (int off = 32; off; off >>= 1) lt += __shfl_xor(lt, off, 64);
    if (tid == 0) outp[0] = lt * (1.f / 64.f);
  }
}

extern "C" void kernel_launch(void* const* d_in, const int* in_sizes, int n_in,
                              void* d_out, int out_size, void* d_ws, size_t ws_size,
                              hipStream_t stream) {
  const float* x = (const float*)d_in[0];
  const float* tlbl = (const float*)d_in[1];
  const float* maskp = (const float*)d_in[2];
  const float* Wih = (const float*)d_in[3];
  const float* Whh = (const float*)d_in[4];
  const float* bih = (const float*)d_in[5];
  const float* bhh = (const float*)d_in[6];
  const float* gammap = (const float*)d_in[7];
  const float* betap = (const float*)d_in[8];
  const float* fcw = (const float*)d_in[9];
  const float* fcb = (const float*)d_in[10];
  float* outp = (float*)d_out;

  // ws: slots(512B)+pad @0 | hbuf 2x128KB @4KB | partial 32KB | xbf 20.5MB
  unsigned* slots = (unsigned*)d_ws;
  unsigned short* hbuf = (unsigned short*)((char*)d_ws + 4096);
  float* partial = (float*)((char*)d_ws + 4096 + 2 * BB * HH * 2);
  unsigned short* xbf =
      (unsigned short*)((char*)d_ws + 4096 + 2 * BB * HH * 2 + BB * NBLK * 4);

  // zero slots + h image 0 (contiguous from ws base: 4096 + 128KB)
  int ndw = (4096 + BB * HH * 2) / 4;
  hipLaunchKernelGGL(init_k, dim3(64), dim3(NTH), 0, stream, (unsigned*)d_ws, ndw);
  hipLaunchKernelGGL(xcvt_k, dim3(2048), dim3(NTH), 0, stream, x, xbf);
  hipLaunchKernelGGL(lstm_mfma, dim3(NBLK), dim3(NTH), 0, stream,
                     Wih, Whh, bih, bhh, gammap, betap, maskp, tlbl, fcw, fcb,
                     xbf, hbuf, partial, slots, outp);
}

// Round 17
// 2628.862 us; speedup vs baseline: 1.3710x; 1.0101x over previous
//
#include <hip/hip_runtime.h>
#include <cstddef>
#include <cstdint>

#define BB 64
#define TT 512
#define HH 1024
#define DD 300
#define NTH 256
#define NBLK 128
#define HB 8                  // h-indices per block
#define XPAD 320              // x K padded to 10*32
#define KS_X 10
#define KS_H 32
#define SLOTSTRIDE 16         // dwords: one slot per 64B IC line (anti-contention)
#define BN_EPS 1e-5f

typedef short short8 __attribute__((ext_vector_type(8)));
typedef float f32x4 __attribute__((ext_vector_type(4)));
typedef unsigned u32x2 __attribute__((ext_vector_type(2)));
typedef unsigned u32x4 __attribute__((ext_vector_type(4)));

__device__ __forceinline__ float sigmoid_f(float v) {
  v = fminf(fmaxf(v, -30.f), 30.f);
  return 1.f / (1.f + __expf(-v));
}
__device__ __forceinline__ float tanh_f(float v) {
  float e = __expf(fminf(fmaxf(2.f * v, -30.f), 30.f));
  return (e - 1.f) / (e + 1.f);
}
__device__ __forceinline__ unsigned short tobf(float f) {
  unsigned u = __float_as_uint(f);
  u += 0x7fffu + ((u >> 16) & 1u);
  return (unsigned short)(u >> 16);
}

// ---- all in-loop vmem is inline asm so counted-vmcnt bookkeeping stays exact
__device__ __forceinline__ void ldA_sc(const void* p, short8& d) {
  asm volatile("global_load_dwordx4 %0, %1, off sc0 sc1"
               : "=v"(d) : "v"(p) : "memory");
}
__device__ __forceinline__ void ldA_nc(const void* p, short8& d) {
  asm volatile("global_load_dwordx4 %0, %1, off"
               : "=v"(d) : "v"(p) : "memory");
}
__device__ __forceinline__ void ld4_sc(const void* p, f32x4& d) {
  asm volatile("global_load_dwordx4 %0, %1, off sc0 sc1"
               : "=v"(d) : "v"(p) : "memory");
}
__device__ __forceinline__ void st_sc32(void* p, unsigned v) {  // with drain
  asm volatile("global_store_dword %0, %1, off sc0 sc1\n\ts_waitcnt vmcnt(0)"
               :: "v"(p), "v"(v) : "memory");
}
__device__ __forceinline__ void st_sc32_nd(void* p, unsigned v) {  // no drain
  asm volatile("global_store_dword %0, %1, off sc0 sc1"
               :: "v"(p), "v"(v) : "memory");
}
__device__ __forceinline__ void st4_sc_nd(void* p, u32x4 v) {  // no drain
  asm volatile("global_store_dwordx4 %0, %1, off sc0 sc1"
               :: "v"(p), "v"(v) : "memory");
}
#define WAITV(N)                                                   \
  do {                                                             \
    asm volatile("s_waitcnt vmcnt(" #N ")" ::: "memory");          \
    __builtin_amdgcn_sched_barrier(0);                             \
  } while (0)

__device__ __forceinline__ f32x4 mfma16(short8 a, short8 b, f32x4 c) {
  return __builtin_amdgcn_mfma_f32_16x16x32_bf16(a, b, c, 0, 0, 0);
}

// wave0-only poll: lane i checks slots (line-padded: one per 64B line) at
// indices 2i and 2i+1. Drained probes (same ledger behavior as before).
// PRECONDITION: wave0 calls this only AFTER its own block's slot is raised.
__device__ __forceinline__ void poll_ge(const unsigned* slots, int tid, unsigned ep) {
  int it = 0;
  for (;;) {
    int ok = 1;
    if (tid < 64) {
      unsigned a, b2;
      asm volatile("global_load_dword %0, %2, off sc0 sc1\n\t"
                   "global_load_dword %1, %3, off sc0 sc1\n\t"
                   "s_waitcnt vmcnt(0)"
                   : "=&v"(a), "=v"(b2)
                   : "v"(&slots[(2 * tid) * SLOTSTRIDE]),
                     "v"(&slots[(2 * tid + 1) * SLOTSTRIDE])
                   : "memory");
      ok = (a >= ep && b2 >= ep) ? 1 : 0;
    }
    if (__syncthreads_and(ok)) break;
    if (++it > (1 << 20)) break;  // valve: fail visibly, never hang
    if (it > 2) __builtin_amdgcn_s_sleep(1);
  }
}

__global__ void init_k(unsigned* __restrict__ base, int ndw) {
  int idx = blockIdx.x * blockDim.x + threadIdx.x;
  for (int i = idx; i < ndw; i += gridDim.x * blockDim.x) st_sc32(base + i, 0u);
}

// x [b][t][d] f32 -> xbf [t][b][XPAD] bf16 (zero-padded)
__global__ void xcvt_k(const float* __restrict__ x, unsigned short* __restrict__ xbf) {
  const int total = TT * BB * XPAD;
  for (int idx = blockIdx.x * blockDim.x + threadIdx.x; idx < total;
       idx += gridDim.x * blockDim.x) {
    int kx = idx % XPAD;
    int tb = idx / XPAD;
    int b = tb % BB, t = tb / BB;
    float v = (kx < DD) ? x[(size_t)b * (TT * DD) + (size_t)t * DD + kx] : 0.f;
    xbf[idx] = tobf(v);
  }
}

__global__ void __launch_bounds__(NTH, 1)
lstm_mfma(const float* __restrict__ Wih, const float* __restrict__ Whh,
          const float* __restrict__ bih, const float* __restrict__ bhh,
          const float* __restrict__ gammap, const float* __restrict__ betap,
          const float* __restrict__ maskp, const float* __restrict__ tlbl,
          const float* __restrict__ fcw, const float* __restrict__ fcb,
          const unsigned short* __restrict__ xbf, unsigned short* __restrict__ hbuf,
          float* __restrict__ partial, unsigned* __restrict__ slots,
          float* __restrict__ outp) {
  // B-operand fragments: Wlds[nt][ks][lane] = 8 bf16 of
  // B[k = ks*32 + (lane>>4)*8 + e][col = nt*16 + (lane&15)].
  // ks 0..31 = W_hh, 32..41 = W_ih (zero-padded). Lane-linear ds_read_b128.
  __shared__ short8 Wlds[2][KS_H + KS_X][64];  // 84 KB
  __shared__ float Cs[64][33];                 // 8.4 KB (+1 pad)
  __shared__ unsigned pkbuf[BB][4];            // 1 KB staged publish
  __shared__ float red_s[4][64];               // 1 KB

  const int tid = threadIdx.x;
  const int w = tid >> 6, l = tid & 63;
  const int blk = blockIdx.x;
  const int hb0 = blk * HB;

  // ---- stage W as bf16 fragments (once) ----
  for (int idx = tid; idx < 2 * (KS_H + KS_X) * 64; idx += NTH) {
    int nt = idx / ((KS_H + KS_X) * 64);
    int rem = idx % ((KS_H + KS_X) * 64);
    int ks = rem >> 6, ll = rem & 63;
    int colq = nt * 16 + (ll & 15);
    int g = colq >> 3, j = colq & 7;
    int r = g * HH + hb0 + j;
    int k0 = (ll >> 4) * 8;
    float v[8];
    if (ks < KS_H) {
      const float* src = Whh + (size_t)r * HH + ks * 32 + k0;
      f32x4 u0 = *(const f32x4*)src;
      f32x4 u1 = *(const f32x4*)(src + 4);
      v[0] = u0.x; v[1] = u0.y; v[2] = u0.z; v[3] = u0.w;
      v[4] = u1.x; v[5] = u1.y; v[6] = u1.z; v[7] = u1.w;
    } else {
      int d0 = (ks - KS_H) * 32 + k0;
#pragma unroll
      for (int e = 0; e < 8; ++e)
        v[e] = (d0 + e < DD) ? Wih[(size_t)r * DD + d0 + e] : 0.f;
    }
    short8 pk;
#pragma unroll
    for (int e = 0; e < 8; ++e) pk[e] = (short)tobf(v[e]);
    Wlds[nt][ks][ll] = pk;
  }

  // ---- MFMA roles: wave = M-tile; computes both N-tiles ----
  const int row = w * 16 + (l & 15);
  const int lk16 = (l >> 4);

  // per-column combined bias (folded into acc init)
  const int cq = l & 15;
  const float bcol0 = bih[(cq >> 3) * HH + hb0 + (cq & 7)] +
                      bhh[(cq >> 3) * HH + hb0 + (cq & 7)];
  const float bcol1 = bih[(2 + (cq >> 3)) * HH + hb0 + (cq & 7)] +
                      bhh[(2 + (cq >> 3)) * HH + hb0 + (cq & 7)];

  // ---- pointwise roles: lane = batch, wave w -> h-sub j0=2w, j1=2w+1 ----
  const int b = l, j0 = 2 * w, j1 = 2 * w + 1;
  const float gam0 = gammap[hb0 + j0], gam1 = gammap[hb0 + j1];
  const float bet0 = betap[hb0 + j0], bet1 = betap[hb0 + j1];
  const float msk0 = maskp[(size_t)b * HH + hb0 + j0];
  const float msk1 = maskp[(size_t)b * HH + hb0 + j1];
  const float fw0 = fcw[hb0 + j0], fw1 = fcw[hb0 + j1];
  float creg0 = 0.f, creg1 = 0.f;
  float pool0 = -3.4e38f, pool1 = -3.4e38f;

  // prologue: issue x-loads for s=0
  short8 xa[KS_X];
  {
    const unsigned short* px = xbf + ((size_t)0 * BB + row) * XPAD + lk16 * 8;
#pragma unroll
    for (int i = 0; i < KS_X; ++i) ldA_nc(px + i * 32, xa[i]);
  }
  __syncthreads();  // Wlds visible

  for (int s = 0; s < TT; ++s) {
    const unsigned short* hc = hbuf + (size_t)(s & 1) * (BB * HH);
    unsigned short* hnx = hbuf + (size_t)((s + 1) & 1) * (BB * HH);

    // wait for h_s publication (s=0 passes immediately; own slot already
    // raised by THIS wave0 before it entered the poll -> no own-slot race)
    poll_ge(slots, tid, (unsigned)s);

    // issue ALL 32 h A-frag loads (addr = hc + (ks*4 + lk16)*512 + row*8)
    const unsigned short* ph = hc + (size_t)lk16 * 512 + row * 8;
    short8 ha[KS_H];
#pragma unroll
    for (int i = 0; i < KS_H; ++i) ldA_sc(ph + i * 2048, ha[i]);

    // Per-wave queues here: w0 = [h32] (x+pub drained at its WAITV(0), slot
    // drained by poll probe), w1-3 = [x10, h32] = 42 -> WAITV(32) retires x
    // exactly (x had pointwise+publish+poll window to land).
    WAITV(32);

    // x-MFMAs while h chunk0 is in flight; 4 independent acc chains
    f32x4 acc0a = {bcol0, bcol0, bcol0, bcol0}, acc0b = {0.f, 0.f, 0.f, 0.f};
    f32x4 acc1a = {bcol1, bcol1, bcol1, bcol1}, acc1b = {0.f, 0.f, 0.f, 0.f};
#pragma unroll
    for (int i = 0; i < KS_X; i += 2) {
      acc0a = mfma16(xa[i], Wlds[0][KS_H + i][l], acc0a);
      acc1a = mfma16(xa[i], Wlds[1][KS_H + i][l], acc1a);
      acc0b = mfma16(xa[i + 1], Wlds[0][KS_H + i + 1][l], acc0b);
      acc1b = mfma16(xa[i + 1], Wlds[1][KS_H + i + 1][l], acc1b);
    }
    WAITV(24);  // h chunk0 (loads 0..7) done
#pragma unroll
    for (int i = 0; i < 8; i += 2) {
      acc0a = mfma16(ha[i], Wlds[0][i][l], acc0a);
      acc1a = mfma16(ha[i], Wlds[1][i][l], acc1a);
      acc0b = mfma16(ha[i + 1], Wlds[0][i + 1][l], acc0b);
      acc1b = mfma16(ha[i + 1], Wlds[1][i + 1][l], acc1b);
    }
    WAITV(16);  // chunk1
#pragma unroll
    for (int i = 8; i < 16; i += 2) {
      acc0a = mfma16(ha[i], Wlds[0][i][l], acc0a);
      acc1a = mfma16(ha[i], Wlds[1][i][l], acc1a);
      acc0b = mfma16(ha[i + 1], Wlds[0][i + 1][l], acc0b);
      acc1b = mfma16(ha[i + 1], Wlds[1][i + 1][l], acc1b);
    }
    WAITV(8);  // chunk2
#pragma unroll
    for (int i = 16; i < 24; i += 2) {
      acc0a = mfma16(ha[i], Wlds[0][i][l], acc0a);
      acc1a = mfma16(ha[i], Wlds[1][i][l], acc1a);
      acc0b = mfma16(ha[i + 1], Wlds[0][i + 1][l], acc0b);
      acc1b = mfma16(ha[i + 1], Wlds[1][i + 1][l], acc1b);
    }
    WAITV(0);  // chunk3
#pragma unroll
    for (int i = 24; i < 32; i += 2) {
      acc0a = mfma16(ha[i], Wlds[0][i][l], acc0a);
      acc1a = mfma16(ha[i], Wlds[1][i][l], acc1a);
      acc0b = mfma16(ha[i + 1], Wlds[0][i + 1][l], acc0b);
      acc1b = mfma16(ha[i + 1], Wlds[1][i + 1][l], acc1b);
    }
    f32x4 acc0 = acc0a + acc0b, acc1 = acc1a + acc1b;

    // ---- C exchange via LDS (C: col=lane&15, row=(lane>>4)*4+r) ----
    {
      int crow = w * 16 + (l >> 4) * 4;
      int cc0 = (l & 15), cc1 = 16 + (l & 15);
#pragma unroll
      for (int r = 0; r < 4; ++r) {
        Cs[crow + r][cc0] = acc0[r];
        Cs[crow + r][cc1] = acc1[r];
      }
    }
    __syncthreads();

    // ---- x prefetch for s+1 (proven position: has pointwise+publish+poll
    // window to land; retired at wave0's WAITV(0) / others' WAITV(32)) ----
    {
      int sx = (s + 1 < TT) ? s + 1 : s;  // uniform ledger on last iter
      const unsigned short* px = xbf + ((size_t)sx * BB + row) * XPAD + lk16 * 8;
#pragma unroll
      for (int i = 0; i < KS_X; ++i) ldA_nc(px + i * 32, xa[i]);
    }

    // ---- pointwise-lite: ONLY what the recurrence needs (BN deferred) ----
    float gI0 = Cs[b][j0],      gF0 = Cs[b][8 + j0];
    float gG0 = Cs[b][16 + j0], gO0 = Cs[b][24 + j0];
    float gI1 = Cs[b][j1],      gF1 = Cs[b][8 + j1];
    float gG1 = Cs[b][16 + j1], gO1 = Cs[b][24 + j1];
    float c20 = sigmoid_f(gF0) * creg0 + sigmoid_f(gI0) * tanh_f(gG0);
    float h20 = sigmoid_f(gO0) * tanh_f(c20);
    float c21 = sigmoid_f(gF1) * creg1 + sigmoid_f(gI1) * tanh_f(gG1);
    float h21 = sigmoid_f(gO1) * tanh_f(c21);
    creg0 = c20;
    creg1 = c21;
    pkbuf[b][w] = (unsigned)tobf(h20) | ((unsigned)tobf(h21) << 16);
    __syncthreads();

    // ---- wave0: full-line 1KB publish + drain + fire-forget slot, THEN it
    // enters the poll (own slot guaranteed raised before first probe) ----
    if (w == 0) {
      u32x4 pv = {pkbuf[l][0], pkbuf[l][1], pkbuf[l][2], pkbuf[l][3]};
      st4_sc_nd(hnx + (size_t)blk * 512 + l * 8, pv);
      WAITV(0);  // drains publish + this wave's x-prefetch (1 LLC RT)
      if (l == 0) st_sc32_nd(&slots[blk * SLOTSTRIDE], (unsigned)(s + 1));
    }

    // ---- BN + pool: OFF the critical chain (waves 1-3 run this under
    // wave0's publish drain; wave0 runs it after the slot raise) ----
    {
      float s10 = h20, s20 = h20 * h20, s11 = h21, s21 = h21 * h21;
#pragma unroll
      for (int off = 32; off; off >>= 1) {
        s10 += __shfl_xor(s10, off, 64);
        s20 += __shfl_xor(s20, off, 64);
        s11 += __shfl_xor(s11, off, 64);
        s21 += __shfl_xor(s21, off, 64);
      }
      float mu0 = s10 * (1.f / 64.f), var0 = fmaf(-mu0, mu0, s20 * (1.f / 64.f));
      float mu1 = s11 * (1.f / 64.f), var1 = fmaf(-mu1, mu1, s21 * (1.f / 64.f));
      float hn0 = gam0 * (h20 - mu0) * rsqrtf(var0 + BN_EPS) + bet0;
      float hn1 = gam1 * (h21 - mu1) * rsqrtf(var1 + BN_EPS) + bet1;
      pool0 = fmaxf(pool0, hn0 * msk0);
      pool1 = fmaxf(pool1, hn1 * msk1);
    }
  }

  // ---- per-block FC partial ----
  red_s[w][b] = pool0 * fw0 + pool1 * fw1;
  __syncthreads();
  if (tid < BB) {
    float part = red_s[0][tid] + red_s[1][tid] + red_s[2][tid] + red_s[3][tid];
    st_sc32(&partial[(size_t)tid * NBLK + blk], __float_as_uint(part));
  }
  __syncthreads();
  if (tid == 0) st_sc32_nd(&slots[blk * SLOTSTRIDE], (unsigned)(TT + 2));
  if (blk != 0) return;

  // ---- block 0: final reduction + loss ----
  poll_ge(slots, tid, (unsigned)(TT + 2));
  {
    int fb = tid & 63, q = tid >> 6;
    const float* pp = partial + ((size_t)fb * NBLK + q * 32);
    f32x4 v0, v1, v2, v3, v4, v5, v6, v7;
    ld4_sc(pp + 0, v0);  ld4_sc(pp + 4, v1);  ld4_sc(pp + 8, v2);  ld4_sc(pp + 12, v3);
    ld4_sc(pp + 16, v4); ld4_sc(pp + 20, v5); ld4_sc(pp + 24, v6); ld4_sc(pp + 28, v7);
    WAITV(0);
    float sum = v0.x + v0.y + v0.z + v0.w + v1.x + v1.y + v1.z + v1.w +
                v2.x + v2.y + v2.z + v2.w + v3.x + v3.y + v3.z + v3.w +
                v4.x + v4.y + v4.z + v4.w + v5.x + v5.y + v5.z + v5.w +
                v6.x + v6.y + v6.z + v6.w + v7.x + v7.y + v7.z + v7.w;
    red_s[q][fb] = sum;
  }
  __syncthreads();
  if (tid < BB) {
    float z = red_s[0][tid] + red_s[1][tid] + red_s[2][tid] + red_s[3][tid] + fcb[0];
    outp[1 + tid] = z;
    float sp = fmaxf(z, 0.f) + log1pf(__expf(-fabsf(z)));
    float lt = sp - z * tlbl[tid];
#pragma unroll
    for (int off = 32; off; off >>= 1) lt += __shfl_xor(lt, off, 64);
    if (tid == 0) outp[0] = lt * (1.f / 64.f);
  }
}

extern "C" void kernel_launch(void* const* d_in, const int* in_sizes, int n_in,
                              void* d_out, int out_size, void* d_ws, size_t ws_size,
                              hipStream_t stream) {
  const float* x = (const float*)d_in[0];
  const float* tlbl = (const float*)d_in[1];
  const float* maskp = (const float*)d_in[2];
  const float* Wih = (const float*)d_in[3];
  const float* Whh = (const float*)d_in[4];
  const float* bih = (const float*)d_in[5];
  const float* bhh = (const float*)d_in[6];
  const float* gammap = (const float*)d_in[7];
  const float* betap = (const float*)d_in[8];
  const float* fcw = (const float*)d_in[9];
  const float* fcb = (const float*)d_in[10];
  float* outp = (float*)d_out;

  // ws: slots line-padded 8KB (+pad to 16KB) @0 | hbuf 2x128KB @16KB
  //     | partial 32KB | xbf 20.5MB
  unsigned* slots = (unsigned*)d_ws;
  unsigned short* hbuf = (unsigned short*)((char*)d_ws + 16384);
  float* partial = (float*)((char*)d_ws + 16384 + 2 * BB * HH * 2);
  unsigned short* xbf =
      (unsigned short*)((char*)d_ws + 16384 + 2 * BB * HH * 2 + BB * NBLK * 4);

  // zero slots region + h image 0 (contiguous from ws base: 16KB + 128KB)
  int ndw = (16384 + BB * HH * 2) / 4;
  hipLaunchKernelGGL(init_k, dim3(64), dim3(NTH), 0, stream, (unsigned*)d_ws, ndw);
  hipLaunchKernelGGL(xcvt_k, dim3(2048), dim3(NTH), 0, stream, x, xbf);
  hipLaunchKernelGGL(lstm_mfma, dim3(NBLK), dim3(NTH), 0, stream,
                     Wih, Whh, bih, bhh, gammap, betap, maskp, tlbl, fcw, fcb,
                     xbf, hbuf, partial, slots, outp);
}